// Round 2
// baseline (253.685 us; speedup 1.0000x reference)
//
#include <hip/hip_runtime.h>
#include <hip/hip_bf16.h>

#define B_ 4
#define T_ 64
#define N_ 325
#define F_ 3
#define DH 16
#define DD 64
#define NH 4

// ---------------- K1: S = adj + 2*adj@adj  (325x325, f32 out) ----------------
__global__ void k_support(const float* __restrict__ adj, float* __restrict__ S) {
    int idx = blockIdx.x * 256 + threadIdx.x;
    if (idx >= N_ * N_) return;
    int i = idx / N_, j = idx % N_;
    float acc = 0.f;
    for (int k = 0; k < N_; ++k)
        acc += adj[i * N_ + k] * adj[k * N_ + j];
    S[idx] = adj[idx] + 2.f * acc;
}

// ---------------- K2: X = relu(inputs @ w_lt^T + b_lt)  (B,T,N,16) f32 -------
__global__ void k_lintrans(const float* __restrict__ in,
                           const float* __restrict__ w,    // (16,3)
                           const float* __restrict__ bias, // (16)
                           float* __restrict__ X) {
    int idx = blockIdx.x * 256 + threadIdx.x;   // over B*T*N*16 = 1,331,200
    if (idx >= B_ * T_ * N_ * DH) return;
    int tok = idx >> 4, o = idx & 15;
    float f0 = in[tok * 3 + 0];
    float f1 = in[tok * 3 + 1];
    float f2 = in[tok * 3 + 2];
    float a = bias[o] + f0 * w[o * 3 + 0] + f1 * w[o * 3 + 1] + f2 * w[o * 3 + 2];
    X[idx] = fmaxf(a, 0.f);
}

// ---------------- K3: lfs[b,t,:,:] = S @ X[b,t,:,:]   (256 blocks) -----------
__global__ __launch_bounds__(256) void k_gconv(const float* __restrict__ S,
                                               const float* __restrict__ X,
                                               float* __restrict__ lfs) {
    __shared__ float Xs[N_ * DH];   // 5200 f32 = 20.8 KB
    int bt = blockIdx.x;            // 0..255  (b*T+t)
    const float* Xg = X + (size_t)bt * (N_ * DH);
    for (int m = threadIdx.x; m < N_ * DH; m += 256) Xs[m] = Xg[m];
    __syncthreads();
    for (int idx = threadIdx.x; idx < N_ * DH; idx += 256) {
        int i = idx >> 4, c = idx & 15;
        const float* Sr = S + (size_t)i * N_;
        float acc = 0.f;
        for (int j = 0; j < N_; ++j) acc += Sr[j] * Xs[(j << 4) + c];
        lfs[(size_t)bt * (N_ * DH) + idx] = acc;
    }
}

// ---------------- K4: fused QKV + attention + head-concat + w_ls + residual --
// one block per (b,n); 256 threads = 4 waves (one head each)
__global__ __launch_bounds__(256) void k_attn(
    const float* __restrict__ lfs, const float* __restrict__ X,
    const float* __restrict__ wq, const float* __restrict__ bq,
    const float* __restrict__ wk, const float* __restrict__ bk,
    const float* __restrict__ wv, const float* __restrict__ bv,
    const float* __restrict__ wls, const float* __restrict__ bls,
    float* __restrict__ ypre) {
    __shared__ float Lf[T_][DH];    // 4 KB
    __shared__ float Qs[T_][DD];    // 16 KB (reused for head-concat result R)
    __shared__ float Ks[T_][DD];    // 16 KB
    __shared__ float Vs[T_][DD];    // 16 KB
    int b = blockIdx.x / N_, n = blockIdx.x % N_;
    int tid = threadIdx.x;

    // load lfs rows for this (b,n): (64,16)
    for (int idx = tid; idx < T_ * DH; idx += 256) {
        int t = idx >> 4, c = idx & 15;
        Lf[t][c] = lfs[(((size_t)(b * T_ + t) * N_ + n) << 4) + c];
    }
    __syncthreads();

    // QKV: each thread owns fixed output column o = tid&63, 16 rows
    {
        int o = tid & 63;
        float wqc[DH], wkc[DH], wvc[DH];
#pragma unroll
        for (int c = 0; c < DH; ++c) {
            wqc[c] = wq[c * DD + o];
            wkc[c] = wk[c * DD + o];
            wvc[c] = wv[c * DD + o];
        }
        float bqo = bq[o], bko = bk[o], bvo = bv[o];
        for (int t = tid >> 6; t < T_; t += 4) {
            float aq = bqo, ak = bko, av = bvo;
#pragma unroll
            for (int c = 0; c < DH; ++c) {
                float x = Lf[t][c];
                aq += x * wqc[c]; ak += x * wkc[c]; av += x * wvc[c];
            }
            Qs[t][o] = fmaxf(aq, 0.f);
            Ks[t][o] = fmaxf(ak, 0.f);
            Vs[t][o] = fmaxf(av, 0.f);
        }
    }
    __syncthreads();

    // attention: wave = head, lane = query row t
    {
        int h = tid >> 6;    // 0..3
        int t = tid & 63;    // query row
        float q[DH];
#pragma unroll
        for (int c = 0; c < DH; ++c) q[c] = Qs[t][h * DH + c];
        float p[T_];
        float m = -1e30f;
#pragma unroll
        for (int s = 0; s < T_; ++s) {
            float acc = 0.f;
#pragma unroll
            for (int c = 0; c < DH; ++c) acc += q[c] * Ks[s][h * DH + c];
            acc *= 0.25f;          // 1/sqrt(16)
            p[s] = acc;
            m = fmaxf(m, acc);
        }
        float sum = 0.f;
#pragma unroll
        for (int s = 0; s < T_; ++s) { float e = __expf(p[s] - m); p[s] = e; sum += e; }
        float inv = 1.f / sum;
        float r[DH];
#pragma unroll
        for (int c = 0; c < DH; ++c) r[c] = 0.f;
#pragma unroll
        for (int s = 0; s < T_; ++s) {
            float a = (s <= t) ? p[s] * inv : 1e-9f;   // tril mask AFTER softmax
#pragma unroll
            for (int c = 0; c < DH; ++c) r[c] += a * Vs[s][h * DH + c];
        }
        __syncthreads();           // everyone done reading Qs
#pragma unroll
        for (int c = 0; c < DH; ++c) Qs[t][h * DH + c] = fmaxf(r[c], 0.f);  // R := relu(attn@V)
    }
    __syncthreads();

    // output projection (64 -> 16) + residual, write y_pre (f32, token layout)
    {
        int oo = tid & 15;
        float wl[DD];
#pragma unroll
        for (int k = 0; k < DD; ++k) wl[k] = wls[oo * DD + k];
        float bo = bls[oo];
        for (int tt = tid >> 4; tt < T_; tt += 16) {
            float acc = bo;
#pragma unroll
            for (int k = 0; k < DD; ++k) acc += wl[k] * Qs[tt][k];
            size_t gi = (((size_t)(b * T_ + tt) * N_ + n) << 4) + oo;
            ypre[gi] = X[gi] + fmaxf(acc, 0.f);
        }
    }
}

// ---------------- K5: per-batch partial sums (64 chunks per batch) -----------
__global__ __launch_bounds__(256) void k_lnpart(const float* __restrict__ y, float* __restrict__ part) {
    __shared__ float ssum[256], ssq[256];
    int b = blockIdx.x >> 6, chunk = blockIdx.x & 63;
    const float* yb = y + (size_t)b * 332800 + (size_t)chunk * 5200;
    float s = 0.f, q2 = 0.f;
    for (int i = threadIdx.x; i < 5200; i += 256) { float v = yb[i]; s += v; q2 += v * v; }
    ssum[threadIdx.x] = s; ssq[threadIdx.x] = q2;
    __syncthreads();
    for (int st = 128; st > 0; st >>= 1) {
        if (threadIdx.x < st) {
            ssum[threadIdx.x] += ssum[threadIdx.x + st];
            ssq[threadIdx.x] += ssq[threadIdx.x + st];
        }
        __syncthreads();
    }
    if (threadIdx.x == 0) { part[blockIdx.x * 2] = ssum[0]; part[blockIdx.x * 2 + 1] = ssq[0]; }
}

// ---------------- K5b: finalize mu / rsigma per batch ------------------------
__global__ void k_lnstat(const float* __restrict__ part, float* __restrict__ stat) {
    int b = blockIdx.x;
    if (threadIdx.x == 0) {
        float s = 0.f, q = 0.f;
        for (int c = 0; c < 64; ++c) { s += part[(b * 64 + c) * 2]; q += part[(b * 64 + c) * 2 + 1]; }
        float mu = s / 332800.f;
        float var = q / 332800.f - mu * mu;
        stat[b * 2] = mu;
        stat[b * 2 + 1] = rsqrtf(var + 1e-5f);
    }
}

// ---------------- K6: normalize + gamma/beta + f32 store ---------------------
__global__ __launch_bounds__(256) void k_lnapply(const float* __restrict__ y,
                                                 const float* __restrict__ stat,
                                                 const float* __restrict__ gamma,
                                                 const float* __restrict__ beta,
                                                 float* __restrict__ out) {
    int idx = blockIdx.x * 256 + threadIdx.x;
    if (idx >= B_ * T_ * N_ * DH) return;
    int b = idx / 332800;
    int r = idx - b * 332800;
    int c = r & 15;
    int tn = r >> 4;            // t*325 + n
    int t = tn / N_, n = tn - t * N_;
    int g = (c * T_ + t) * N_ + n;   // gamma/beta are (d, T, N)
    float mu = stat[b * 2], rs = stat[b * 2 + 1];
    out[idx] = (y[idx] - mu) * rs * gamma[g] + beta[g];
}

extern "C" void kernel_launch(void* const* d_in, const int* in_sizes, int n_in,
                              void* d_out, int out_size, void* d_ws, size_t ws_size,
                              hipStream_t stream) {
    const float* in   = (const float*)d_in[0];
    const float* adj  = (const float*)d_in[1];
    const float* w_lt = (const float*)d_in[2];
    const float* b_lt = (const float*)d_in[3];
    const float* wq   = (const float*)d_in[4];
    const float* bq   = (const float*)d_in[5];
    const float* wk   = (const float*)d_in[6];
    const float* bk   = (const float*)d_in[7];
    const float* wv   = (const float*)d_in[8];
    const float* bv   = (const float*)d_in[9];
    const float* wls  = (const float*)d_in[10];
    const float* bls  = (const float*)d_in[11];
    const float* gam  = (const float*)d_in[12];
    const float* bet  = (const float*)d_in[13];
    float* out = (float*)d_out;

    float* ws = (float*)d_ws;
    float* S    = ws;                       // 105,625 -> pad 105,728
    float* X    = S + 105728;               // 1,331,200
    float* lfs  = X + 1331200;              // 1,331,200
    float* ypre = lfs + 1331200;            // 1,331,200
    float* part = ypre + 1331200;           // 512
    float* stat = part + 512;               // 8

    k_support<<<(N_ * N_ + 255) / 256, 256, 0, stream>>>(adj, S);
    k_lintrans<<<(B_ * T_ * N_ * DH) / 256, 256, 0, stream>>>(in, w_lt, b_lt, X);
    k_gconv<<<B_ * T_, 256, 0, stream>>>(S, X, lfs);
    k_attn<<<B_ * N_, 256, 0, stream>>>(lfs, X, wq, bq, wk, bk, wv, bv, wls, bls, ypre);
    k_lnpart<<<256, 256, 0, stream>>>(ypre, part);
    k_lnstat<<<4, 64, 0, stream>>>(part, stat);
    k_lnapply<<<(B_ * T_ * N_ * DH) / 256, 256, 0, stream>>>(ypre, stat, gam, bet, out);
}

// Round 3
// 171.587 us; speedup vs baseline: 1.4785x; 1.4785x over previous
//
#include <hip/hip_runtime.h>
#include <hip/hip_bf16.h>

#define B_ 4
#define T_ 64
#define N_ 325
#define F_ 3
#define DH 16
#define DD 64
#define NH 4
#define BT_ 256                 // B*T
#define M_ 4096                 // BT*DH  (GEMM N-dim)

// ---------------- K1: S = adj + 2*adj@adj  (325x325, f32 out) ----------------
__global__ void k_support(const float* __restrict__ adj, float* __restrict__ S) {
    int idx = blockIdx.x * 256 + threadIdx.x;
    if (idx >= N_ * N_) return;
    int i = idx / N_, j = idx % N_;
    float acc = 0.f;
#pragma unroll 4
    for (int k = 0; k < N_; ++k)
        acc += adj[i * N_ + k] * adj[k * N_ + j];
    S[idx] = adj[idx] + 2.f * acc;
}

// ---------------- K2: X2[n][bt][c] = relu(inputs @ w_lt^T + b_lt) ------------
__global__ void k_lintrans(const float* __restrict__ in,
                           const float* __restrict__ w,    // (16,3)
                           const float* __restrict__ bias, // (16)
                           float* __restrict__ X2) {
    int idx = blockIdx.x * 256 + threadIdx.x;   // over N*BT*16 = 1,331,200 (X2 order)
    if (idx >= N_ * M_) return;
    int n = idx >> 12;          // 4096 per n
    int r = idx & 4095;
    int bt = r >> 4, c = r & 15;
    int tok = bt * N_ + n;      // (b*64+t)*325 + n
    float f0 = in[tok * 3 + 0];
    float f1 = in[tok * 3 + 1];
    float f2 = in[tok * 3 + 2];
    float a = bias[c] + f0 * w[c * 3 + 0] + f1 * w[c * 3 + 1] + f2 * w[c * 3 + 2];
    X2[idx] = fmaxf(a, 0.f);
}

// ---------------- K3: lfs2(325 x 4096) = S(325x325) @ X2(325x4096) -----------
// 64x64 block tile, 4x4 micro-tile, K-tile 32. grid = (64 m-tiles, 6 i-tiles)
#define GK 32
__global__ __launch_bounds__(256) void k_gconv(const float* __restrict__ S,
                                               const float* __restrict__ X2,
                                               float* __restrict__ lfs2) {
    __shared__ float As[GK][68];    // A^T: As[j][i], padded to 68 for banks
    __shared__ float Bs[GK][64];    // Bs[j][m]
    int m0 = blockIdx.x * 64;
    int i0 = blockIdx.y * 64;
    int tid = threadIdx.x;
    int ti = tid & 15, tm = tid >> 4;   // 4x4 micro-tile owner

    float acc[4][4];
#pragma unroll
    for (int a = 0; a < 4; ++a)
#pragma unroll
        for (int bq = 0; bq < 4; ++bq) acc[a][bq] = 0.f;

    for (int k0 = 0; k0 < N_; k0 += GK) {
        // stage A^T: As[j][r] = S[i0+r][k0+j]  (2048 elems, 8 per thread)
#pragma unroll
        for (int p = 0; p < 8; ++p) {
            int e = tid + p * 256;
            int j = e & 31, r = e >> 5;
            int row = i0 + r, col = k0 + j;
            As[j][r] = (row < N_ && col < N_) ? S[row * N_ + col] : 0.f;
        }
        // stage B: Bs[j][m] = X2[(k0+j)*4096 + m0+m]
#pragma unroll
        for (int p = 0; p < 8; ++p) {
            int e = tid + p * 256;
            int mm = e & 63, j = e >> 6;
            int col = k0 + j;
            Bs[j][mm] = (col < N_) ? X2[(size_t)col * M_ + m0 + mm] : 0.f;
        }
        __syncthreads();
#pragma unroll
        for (int j = 0; j < GK; ++j) {
            float a0 = As[j][ti * 4 + 0], a1 = As[j][ti * 4 + 1];
            float a2 = As[j][ti * 4 + 2], a3 = As[j][ti * 4 + 3];
            float b0 = Bs[j][tm * 4 + 0], b1 = Bs[j][tm * 4 + 1];
            float b2 = Bs[j][tm * 4 + 2], b3 = Bs[j][tm * 4 + 3];
            acc[0][0] += a0 * b0; acc[0][1] += a0 * b1; acc[0][2] += a0 * b2; acc[0][3] += a0 * b3;
            acc[1][0] += a1 * b0; acc[1][1] += a1 * b1; acc[1][2] += a1 * b2; acc[1][3] += a1 * b3;
            acc[2][0] += a2 * b0; acc[2][1] += a2 * b1; acc[2][2] += a2 * b2; acc[2][3] += a2 * b3;
            acc[3][0] += a3 * b0; acc[3][1] += a3 * b1; acc[3][2] += a3 * b2; acc[3][3] += a3 * b3;
        }
        __syncthreads();
    }
#pragma unroll
    for (int a = 0; a < 4; ++a) {
        int i = i0 + ti * 4 + a;
        if (i < N_) {
            float* dst = lfs2 + (size_t)i * M_ + m0 + tm * 4;
            dst[0] = acc[a][0]; dst[1] = acc[a][1]; dst[2] = acc[a][2]; dst[3] = acc[a][3];
        }
    }
}

// ---------------- K4: fused QKV + attention + head-concat + w_ls + residual --
// one block per (b,n); 256 threads = 4 waves (one head each)
__global__ __launch_bounds__(256) void k_attn(
    const float* __restrict__ lfs2, const float* __restrict__ X2,
    const float* __restrict__ wq, const float* __restrict__ bq,
    const float* __restrict__ wk, const float* __restrict__ bk,
    const float* __restrict__ wv, const float* __restrict__ bv,
    const float* __restrict__ wls, const float* __restrict__ bls,
    float* __restrict__ ypre) {
    __shared__ float Lf[T_][DH];    // 4 KB
    __shared__ float Qs[T_][DD];    // 16 KB (reused for head-concat result R)
    __shared__ float Ks[T_][DD];    // 16 KB
    __shared__ float Vs[T_][DD];    // 16 KB
    int b = blockIdx.x / N_, n = blockIdx.x % N_;
    int tid = threadIdx.x;
    const float* Lsrc = lfs2 + (size_t)n * M_ + b * (T_ * DH);   // 1024 contiguous

    for (int idx = tid; idx < T_ * DH; idx += 256)
        ((float*)Lf)[idx] = Lsrc[idx];
    __syncthreads();

    // QKV: each thread owns fixed output column o = tid&63, 16 rows
    {
        int o = tid & 63;
        float wqc[DH], wkc[DH], wvc[DH];
#pragma unroll
        for (int c = 0; c < DH; ++c) {
            wqc[c] = wq[c * DD + o];
            wkc[c] = wk[c * DD + o];
            wvc[c] = wv[c * DD + o];
        }
        float bqo = bq[o], bko = bk[o], bvo = bv[o];
        for (int t = tid >> 6; t < T_; t += 4) {
            float aq = bqo, ak = bko, av = bvo;
#pragma unroll
            for (int c = 0; c < DH; ++c) {
                float x = Lf[t][c];
                aq += x * wqc[c]; ak += x * wkc[c]; av += x * wvc[c];
            }
            Qs[t][o] = fmaxf(aq, 0.f);
            Ks[t][o] = fmaxf(ak, 0.f);
            Vs[t][o] = fmaxf(av, 0.f);
        }
    }
    __syncthreads();

    // attention: wave = head, lane = query row t
    {
        int h = tid >> 6;    // 0..3
        int t = tid & 63;    // query row
        float q[DH];
#pragma unroll
        for (int c = 0; c < DH; ++c) q[c] = Qs[t][h * DH + c];
        float p[T_];
        float m = -1e30f;
#pragma unroll
        for (int s = 0; s < T_; ++s) {
            float acc = 0.f;
#pragma unroll
            for (int c = 0; c < DH; ++c) acc += q[c] * Ks[s][h * DH + c];
            acc *= 0.25f;          // 1/sqrt(16)
            p[s] = acc;
            m = fmaxf(m, acc);
        }
        float sum = 0.f;
#pragma unroll
        for (int s = 0; s < T_; ++s) { float e = __expf(p[s] - m); p[s] = e; sum += e; }
        float inv = 1.f / sum;
        float r[DH];
#pragma unroll
        for (int c = 0; c < DH; ++c) r[c] = 0.f;
#pragma unroll
        for (int s = 0; s < T_; ++s) {
            float a = (s <= t) ? p[s] * inv : 1e-9f;   // tril mask AFTER softmax
#pragma unroll
            for (int c = 0; c < DH; ++c) r[c] += a * Vs[s][h * DH + c];
        }
        __syncthreads();           // everyone done reading Qs
#pragma unroll
        for (int c = 0; c < DH; ++c) Qs[t][h * DH + c] = fmaxf(r[c], 0.f);  // R := relu(attn@V)
    }
    __syncthreads();

    // output projection (64 -> 16) + residual, write y_pre (f32, token layout)
    {
        int oo = tid & 15;
        float wl[DD];
#pragma unroll
        for (int k = 0; k < DD; ++k) wl[k] = wls[oo * DD + k];
        float bo = bls[oo];
        const float* Xsrc = X2 + (size_t)n * M_ + b * (T_ * DH);
        for (int tt = tid >> 4; tt < T_; tt += 16) {
            float acc = bo;
#pragma unroll
            for (int k = 0; k < DD; ++k) acc += wl[k] * Qs[tt][k];
            size_t gi = (((size_t)(b * T_ + tt) * N_ + n) << 4) + oo;
            ypre[gi] = Xsrc[tt * DH + oo] + fmaxf(acc, 0.f);
        }
    }
}

// ---------------- K5: per-batch partial sums (64 chunks per batch) -----------
__global__ __launch_bounds__(256) void k_lnpart(const float* __restrict__ y, float* __restrict__ part) {
    __shared__ float ssum[256], ssq[256];
    int b = blockIdx.x >> 6, chunk = blockIdx.x & 63;
    const float* yb = y + (size_t)b * 332800 + (size_t)chunk * 5200;
    float s = 0.f, q2 = 0.f;
    for (int i = threadIdx.x; i < 5200; i += 256) { float v = yb[i]; s += v; q2 += v * v; }
    ssum[threadIdx.x] = s; ssq[threadIdx.x] = q2;
    __syncthreads();
    for (int st = 128; st > 0; st >>= 1) {
        if (threadIdx.x < st) {
            ssum[threadIdx.x] += ssum[threadIdx.x + st];
            ssq[threadIdx.x] += ssq[threadIdx.x + st];
        }
        __syncthreads();
    }
    if (threadIdx.x == 0) { part[blockIdx.x * 2] = ssum[0]; part[blockIdx.x * 2 + 1] = ssq[0]; }
}

// ---------------- K5b: finalize mu / rsigma per batch ------------------------
__global__ void k_lnstat(const float* __restrict__ part, float* __restrict__ stat) {
    int b = blockIdx.x;
    if (threadIdx.x == 0) {
        float s = 0.f, q = 0.f;
        for (int c = 0; c < 64; ++c) { s += part[(b * 64 + c) * 2]; q += part[(b * 64 + c) * 2 + 1]; }
        float mu = s / 332800.f;
        float var = q / 332800.f - mu * mu;
        stat[b * 2] = mu;
        stat[b * 2 + 1] = rsqrtf(var + 1e-5f);
    }
}

// ---------------- K6: normalize + gamma/beta + f32 store ---------------------
__global__ __launch_bounds__(256) void k_lnapply(const float* __restrict__ y,
                                                 const float* __restrict__ stat,
                                                 const float* __restrict__ gamma,
                                                 const float* __restrict__ beta,
                                                 float* __restrict__ out) {
    int idx = blockIdx.x * 256 + threadIdx.x;
    if (idx >= B_ * T_ * N_ * DH) return;
    int b = idx / 332800;
    int r = idx - b * 332800;
    int c = r & 15;
    int tn = r >> 4;            // t*325 + n
    int t = tn / N_, n = tn - t * N_;
    int g = (c * T_ + t) * N_ + n;   // gamma/beta are (d, T, N)
    float mu = stat[b * 2], rs = stat[b * 2 + 1];
    out[idx] = (y[idx] - mu) * rs * gamma[g] + beta[g];
}

extern "C" void kernel_launch(void* const* d_in, const int* in_sizes, int n_in,
                              void* d_out, int out_size, void* d_ws, size_t ws_size,
                              hipStream_t stream) {
    const float* in   = (const float*)d_in[0];
    const float* adj  = (const float*)d_in[1];
    const float* w_lt = (const float*)d_in[2];
    const float* b_lt = (const float*)d_in[3];
    const float* wq   = (const float*)d_in[4];
    const float* bq   = (const float*)d_in[5];
    const float* wk   = (const float*)d_in[6];
    const float* bk   = (const float*)d_in[7];
    const float* wv   = (const float*)d_in[8];
    const float* bv   = (const float*)d_in[9];
    const float* wls  = (const float*)d_in[10];
    const float* bls  = (const float*)d_in[11];
    const float* gam  = (const float*)d_in[12];
    const float* bet  = (const float*)d_in[13];
    float* out = (float*)d_out;

    float* ws = (float*)d_ws;
    float* S    = ws;                       // 105,625 -> pad 105,728
    float* X2   = S + 105728;               // 1,331,200  (layout n, bt, c)
    float* lfs2 = X2 + 1331200;             // 1,331,200  (layout n, bt, c)
    float* ypre = lfs2 + 1331200;           // 1,331,200  (token layout b,t,n,c)
    float* part = ypre + 1331200;           // 512
    float* stat = part + 512;               // 8

    k_support<<<(N_ * N_ + 255) / 256, 256, 0, stream>>>(adj, S);
    k_lintrans<<<(N_ * M_) / 256, 256, 0, stream>>>(in, w_lt, b_lt, X2);
    k_gconv<<<dim3(M_ / 64, (N_ + 63) / 64), 256, 0, stream>>>(S, X2, lfs2);
    k_attn<<<B_ * N_, 256, 0, stream>>>(lfs2, X2, wq, bq, wk, bk, wv, bv, wls, bls, ypre);
    k_lnpart<<<256, 256, 0, stream>>>(ypre, part);
    k_lnstat<<<4, 64, 0, stream>>>(part, stat);
    k_lnapply<<<(B_ * T_ * N_ * DH) / 256, 256, 0, stream>>>(ypre, stat, gam, bet, out);
}